// Round 16
// baseline (135.867 us; speedup 1.0000x reference)
//
#include <hip/hip_runtime.h>
#include <stdint.h>
#include <float.h>

// Chamfer distance, B=4, N=M=4096, 3D fp32.
// Outputs (flat, float32): [0] loss, [1..16384] idx12 (float), [16385..32768] idx21.
//
// SEMANTIC CONTRACT (validated R14/R15, absmax 0.0 — do not change):
//   d in f64: d = fma(dx,dx, fma(dy,dy, dz*dz)), dx = x - bx (f64-promoted f32)
//   pick = smallest index j with d_j <= fma(TOL_K(dir), a2 + b2_j, dmin)
//   K12 = 0.6*2^-23, K21 = 0.   dmin = exact f64 min.
//
// R16: f32 prefilter. d32=(a-b)^2 in f32 has rel err <= ~5e-7; band width
// <= 7.2e-8*M. Every exact-band qualifier satisfies
//   d32 <= m32*(1+2e-6) + 2e-7*M32   (2x-margin, provable)
// K1: f32 min sweep -> m32. K2: f32 sweep, survivors (~1/point) get exact
// f64 d appended to a CAP=4 candidate list. K3: dmin/pick from list (true
// argmin provably in list; order-independent => deterministic); overflow
// (counter>CAP, expected never) -> full exact rescan fallback.

constexpr int B_ = 4;
constexpr int N_ = 4096;
constexpr int PTS = 256;
constexpr int TILES = N_ / PTS;          // 16
constexpr int JSPLIT = 8;
constexpr int CHUNK = N_ / JSPLIT;       // 512
constexpr int CAP = 4;
constexpr double EPS32 = 1.1920928955078125e-7;  // 2^-23
constexpr double TOL_K12 = 0.6 * EPS32;
constexpr double TOL_K21 = 0.0;
constexpr double BETA_ = 1.0;
constexpr double GAMMA_ = 1.0;
constexpr double DELTA_ = 0.0;

__global__ void cd_init(unsigned int* __restrict__ m32,
                        unsigned int* __restrict__ cnt) {
    int i = blockIdx.x * blockDim.x + threadIdx.x;
    if (i < 2 * B_ * N_) {
        m32[i] = 0x7F800000u;            // +inf bits
        cnt[i] = 0u;
    }
}

// grid: (TILES*B_*2, JSPLIT); blockIdx.x = tile + TILES*(b + B_*dir)
__global__ __launch_bounds__(256) void cd_min32(
        const float* __restrict__ xyz1, const float* __restrict__ xyz2,
        unsigned int* __restrict__ m32) {
    const int tile  = blockIdx.x % TILES;
    const int b     = (blockIdx.x / TILES) % B_;
    const int dir   = blockIdx.x / (TILES * B_);
    const int split = blockIdx.y;
    const float* A  = dir ? xyz2 : xyz1;
    const float* Bc = dir ? xyz1 : xyz2;

    __shared__ float4 s[CHUNK];          // 8 KiB
    const float* bbase = Bc + ((size_t)b * N_ + (size_t)split * CHUNK) * 3;
    for (int j = threadIdx.x; j < CHUNK; j += PTS)
        s[j] = make_float4(bbase[3 * j], bbase[3 * j + 1], bbase[3 * j + 2], 0.f);
    __syncthreads();

    const int p = tile * PTS + threadIdx.x;
    const float* ap = A + ((size_t)b * N_ + p) * 3;
    const float x = ap[0], y = ap[1], z = ap[2];

    float m = FLT_MAX;
    #pragma unroll 8
    for (int j = 0; j < CHUNK; ++j) {
        float4 bv = s[j];
        float dx = x - bv.x, dy = y - bv.y, dz = z - bv.z;
        float d  = __fmaf_rn(dx, dx, __fmaf_rn(dy, dy, dz * dz));
        m = fminf(m, d);
    }
    const size_t o = ((size_t)dir * B_ + b) * N_ + p;
    atomicMin(&m32[o], __float_as_uint(m));   // d>=0: bits monotonic
}

// same grid; f32 prefilter, exact f64 append for rare survivors
__global__ __launch_bounds__(256) void cd_cand(
        const float* __restrict__ xyz1, const float* __restrict__ xyz2,
        const unsigned int* __restrict__ m32,
        unsigned int* __restrict__ cnt,
        double* __restrict__ entD, unsigned int* __restrict__ entI) {
    const int tile  = blockIdx.x % TILES;
    const int b     = (blockIdx.x / TILES) % B_;
    const int dir   = blockIdx.x / (TILES * B_);
    const int split = blockIdx.y;
    const float* A  = dir ? xyz2 : xyz1;
    const float* Bc = dir ? xyz1 : xyz2;

    __shared__ float4 s[CHUNK];          // {bx,by,bz,b2_f32}
    const float* bbase = Bc + ((size_t)b * N_ + (size_t)split * CHUNK) * 3;
    for (int j = threadIdx.x; j < CHUNK; j += PTS) {
        float bx = bbase[3 * j], by = bbase[3 * j + 1], bz = bbase[3 * j + 2];
        s[j] = make_float4(bx, by, bz, bx * bx + by * by + bz * bz);
    }
    __syncthreads();

    const int p = tile * PTS + threadIdx.x;
    const float* ap = A + ((size_t)b * N_ + p) * 3;
    const float x = ap[0], y = ap[1], z = ap[2];
    const float a2f = x * x + y * y + z * z;

    const size_t o = ((size_t)dir * B_ + b) * N_ + p;
    const float m   = __uint_as_float(m32[o]);
    const float me  = __fmaf_rn(2e-6f, m, m);    // m*(1+2e-6)

    const double xd = (double)x, yd = (double)y, zd = (double)z;

    #pragma unroll 4
    for (int j = 0; j < CHUNK; ++j) {
        float4 bv = s[j];
        float dx = x - bv.x, dy = y - bv.y, dz = z - bv.z;
        float d32 = __fmaf_rn(dx, dx, __fmaf_rn(dy, dy, dz * dz));
        float thr = __fmaf_rn(2e-7f, a2f + bv.w, me);
        if (d32 <= thr) {                         // rare (~1/point over all j)
            double ddx = xd - (double)bv.x;
            double ddy = yd - (double)bv.y;
            double ddz = zd - (double)bv.z;
            double d64 = fma(ddx, ddx, fma(ddy, ddy, ddz * ddz));
            unsigned int slot = atomicAdd(&cnt[o], 1u);
            if (slot < CAP) {
                entD[o * CAP + slot] = d64;
                entI[o * CAP + slot] = (unsigned int)(split * CHUNK + j);
            }
        }
    }
}

// one thread per (dir,b,p): dmin + banded pick from candidate list
__global__ __launch_bounds__(256) void cd_pick(
        const float* __restrict__ xyz1, const float* __restrict__ xyz2,
        const unsigned int* __restrict__ cnt,
        const double* __restrict__ entD, const unsigned int* __restrict__ entI,
        double* __restrict__ dminArr, float* __restrict__ out) {
    const int gid = blockIdx.x * 256 + threadIdx.x;
    if (gid >= 2 * B_ * N_) return;
    const int dir = gid / (B_ * N_);
    const int b   = (gid / N_) % B_;
    const int p   = gid % N_;
    const float* A  = dir ? xyz2 : xyz1;
    const float* Bc = dir ? xyz1 : xyz2;
    const double tolk = dir ? TOL_K21 : TOL_K12;

    const float* ap = A + ((size_t)b * N_ + p) * 3;
    const double x = (double)ap[0], y = (double)ap[1], z = (double)ap[2];
    const double a2 = x * x + y * y + z * z;
    const float* bb = Bc + (size_t)b * N_ * 3;

    const unsigned int c = cnt[gid];
    double dmin = 1.0e300;
    unsigned int pick = 0xFFFFFFFFu;

    if (c <= CAP) {
        for (unsigned int i = 0; i < c; ++i)
            dmin = fmin(dmin, entD[(size_t)gid * CAP + i]);
        for (unsigned int i = 0; i < c; ++i) {
            unsigned int j = entI[(size_t)gid * CAP + i];
            double d = entD[(size_t)gid * CAP + i];
            double bx = (double)bb[3 * j], by = (double)bb[3 * j + 1],
                   bz = (double)bb[3 * j + 2];
            double M = a2 + (bx * bx + by * by + bz * bz);
            if (d <= fma(tolk, M, dmin)) pick = (j < pick) ? j : pick;
        }
    } else {                                      // overflow fallback (never)
        for (int j = 0; j < N_; ++j) {
            double bx = (double)bb[3 * j], by = (double)bb[3 * j + 1],
                   bz = (double)bb[3 * j + 2];
            double dx = x - bx, dy = y - by, dz = z - bz;
            dmin = fmin(dmin, fma(dx, dx, fma(dy, dy, dz * dz)));
        }
        for (int j = 0; j < N_; ++j) {
            double bx = (double)bb[3 * j], by = (double)bb[3 * j + 1],
                   bz = (double)bb[3 * j + 2];
            double dx = x - bx, dy = y - by, dz = z - bz;
            double d  = fma(dx, dx, fma(dy, dy, dz * dz));
            double M  = a2 + (bx * bx + by * by + bz * bz);
            if (d <= fma(tolk, M, dmin)) { pick = (unsigned int)j; break; }
        }
    }

    dminArr[gid] = dmin;
    const size_t obase = (dir == 0) ? (1 + (size_t)b * N_)
                                    : (1 + (size_t)B_ * N_ + (size_t)b * N_);
    out[obase + p] = (float)pick;
}

__global__ __launch_bounds__(256) void cd_finalize(
        const double* __restrict__ dminArr, float* __restrict__ out,
        double* __restrict__ loss_part) {
    const int b = blockIdx.x;
    const int t = threadIdx.x;

    double sum12 = 0.0, max12 = -1.0e300, sum21 = 0.0;
    for (int n = t; n < N_; n += 256) {
        double d12 = dminArr[(size_t)b * N_ + n];
        double d21 = dminArr[((size_t)B_ + b) * N_ + n];
        sum12 += d12;
        max12 = fmax(max12, d12);
        sum21 += d21;
    }
    __shared__ double s1[256], s2[256], s3[256];
    s1[t] = sum12; s2[t] = max12; s3[t] = sum21;
    __syncthreads();
    for (int off = 128; off > 0; off >>= 1) {
        if (t < off) {
            s1[t] += s1[t + off];
            s2[t]  = fmax(s2[t], s2[t + off]);
            s3[t] += s3[t + off];
        }
        __syncthreads();
    }
    if (t == 0) {
        loss_part[b] = s1[0] / (double)N_ + BETA_ * s2[0]
                     + (GAMMA_ + DELTA_ * (double)N_) * (s3[0] / (double)N_);
    }
}

__global__ void cd_loss(const double* __restrict__ loss_part,
                        float* __restrict__ out) {
    if (blockIdx.x == 0 && threadIdx.x == 0) {
        double s = 0.0;
        for (int b = 0; b < B_; ++b) s += loss_part[b];  // fixed order
        out[0] = (float)(s / (double)B_);
    }
}

extern "C" void kernel_launch(void* const* d_in, const int* in_sizes, int n_in,
                              void* d_out, int out_size, void* d_ws, size_t ws_size,
                              hipStream_t stream) {
    const float* xyz1 = (const float*)d_in[0];
    const float* xyz2 = (const float*)d_in[1];
    float* out = (float*)d_out;

    const size_t NP = (size_t)2 * B_ * N_;       // 32768 points
    double* entD      = (double*)d_ws;           // NP*CAP doubles (1 MiB)
    double* dminArr   = entD + NP * CAP;         // NP doubles (256 KiB)
    double* loss_part = dminArr + NP;            // B_ doubles
    unsigned int* m32 = (unsigned int*)(loss_part + B_);
    unsigned int* cnt = m32 + NP;
    unsigned int* entI = cnt + NP;               // NP*CAP u32 (512 KiB)

    cd_init<<<(int)((NP + 255) / 256), 256, 0, stream>>>(m32, cnt);

    dim3 grid(TILES * B_ * 2, JSPLIT);
    cd_min32<<<grid, PTS, 0, stream>>>(xyz1, xyz2, m32);
    cd_cand <<<grid, PTS, 0, stream>>>(xyz1, xyz2, m32, cnt, entD, entI);

    cd_pick<<<(int)((NP + 255) / 256), 256, 0, stream>>>(
        xyz1, xyz2, cnt, entD, entI, dminArr, out);

    cd_finalize<<<B_, 256, 0, stream>>>(dminArr, out, loss_part);
    cd_loss<<<1, 64, 0, stream>>>(loss_part, out);
}

// Round 17
// 90.154 us; speedup vs baseline: 1.5071x; 1.5071x over previous
//
#include <hip/hip_runtime.h>
#include <stdint.h>
#include <float.h>

// Chamfer distance, B=4, N=M=4096, 3D fp32.
// Outputs (flat, float32): [0] loss, [1..16384] idx12 (float), [16385..32768] idx21.
//
// SEMANTIC CONTRACT (validated R14/R15/R16, absmax 0.0 — do not change):
//   d in f64: d = fma(dx,dx, fma(dy,dy, dz*dz)), dx = x - bx (f64-promoted f32)
//   pick = smallest index j with d_j <= fma(TOL_K(dir), a2 + b2_j, dmin)
//   K12 = 0.6*2^-23, K21 = 0.   dmin = exact f64 min (provably in cand list).
//
// R17: occupancy + overhead. JSPLIT=32 (CHUNK=128), 2 points/thread ->
// grid 2048 blocks = 8 blocks/CU (32 waves, full cap); ds_read amortized over
// 2 points. cd_min32 stores per-(point,split) minima; cd_cand skips splits via
// a conservative monotone bound (splitmin > me + 2e-7*(a2f+b2max_split)) so
// only ~1/32 splits do work. Prefilter margin identical to R16 (2x-proven).

constexpr int B_ = 4;
constexpr int N_ = 4096;
constexpr int PTS = 256;                 // threads per block
constexpr int PPT = 2;                   // points per thread
constexpr int TILES = N_ / (PTS * PPT);  // 8
constexpr int JSPLIT = 32;
constexpr int CHUNK = N_ / JSPLIT;       // 128
constexpr int CAP = 4;
constexpr double EPS32 = 1.1920928955078125e-7;  // 2^-23
constexpr double TOL_K12 = 0.6 * EPS32;
constexpr double TOL_K21 = 0.0;
constexpr double BETA_ = 1.0;
constexpr double GAMMA_ = 1.0;
constexpr double DELTA_ = 0.0;

__global__ void cd_init(unsigned int* __restrict__ m32,
                        unsigned int* __restrict__ cnt) {
    int i = blockIdx.x * blockDim.x + threadIdx.x;
    if (i < 2 * B_ * N_) {
        m32[i] = 0x7F800000u;            // +inf bits
        cnt[i] = 0u;
    }
}

// grid: (TILES*B_*2, JSPLIT); blockIdx.x = tile + TILES*(b + B_*dir)
__global__ __launch_bounds__(256) void cd_min32(
        const float* __restrict__ xyz1, const float* __restrict__ xyz2,
        unsigned int* __restrict__ m32, unsigned int* __restrict__ splitmin) {
    const int tile  = blockIdx.x % TILES;
    const int b     = (blockIdx.x / TILES) % B_;
    const int dir   = blockIdx.x / (TILES * B_);
    const int split = blockIdx.y;
    const float* A  = dir ? xyz2 : xyz1;
    const float* Bc = dir ? xyz1 : xyz2;

    __shared__ float4 s[CHUNK];          // 2 KiB
    const float* bbase = Bc + ((size_t)b * N_ + (size_t)split * CHUNK) * 3;
    if (threadIdx.x < CHUNK) {
        int j = threadIdx.x;
        s[j] = make_float4(bbase[3 * j], bbase[3 * j + 1], bbase[3 * j + 2], 0.f);
    }
    __syncthreads();

    const int p0 = tile * (PTS * PPT) + threadIdx.x;
    const int p1 = p0 + PTS;
    const float* ap0 = A + ((size_t)b * N_ + p0) * 3;
    const float* ap1 = A + ((size_t)b * N_ + p1) * 3;
    const float x0 = ap0[0], y0 = ap0[1], z0 = ap0[2];
    const float x1 = ap1[0], y1 = ap1[1], z1 = ap1[2];

    float m0 = FLT_MAX, m1 = FLT_MAX;
    #pragma unroll 8
    for (int j = 0; j < CHUNK; ++j) {
        float4 bv = s[j];
        float dx0 = x0 - bv.x, dy0 = y0 - bv.y, dz0 = z0 - bv.z;
        float dx1 = x1 - bv.x, dy1 = y1 - bv.y, dz1 = z1 - bv.z;
        m0 = fminf(m0, __fmaf_rn(dx0, dx0, __fmaf_rn(dy0, dy0, dz0 * dz0)));
        m1 = fminf(m1, __fmaf_rn(dx1, dx1, __fmaf_rn(dy1, dy1, dz1 * dz1)));
    }
    const size_t ob = (size_t)dir * B_ + b;
    const size_t sm = (ob * JSPLIT + split) * N_;
    splitmin[sm + p0] = __float_as_uint(m0);     // block-owned: plain store
    splitmin[sm + p1] = __float_as_uint(m1);
    atomicMin(&m32[ob * N_ + p0], __float_as_uint(m0));
    atomicMin(&m32[ob * N_ + p1], __float_as_uint(m1));
}

// same grid; skip splits via conservative bound, exact f64 append for survivors
__global__ __launch_bounds__(256) void cd_cand(
        const float* __restrict__ xyz1, const float* __restrict__ xyz2,
        const unsigned int* __restrict__ m32,
        const unsigned int* __restrict__ splitmin,
        unsigned int* __restrict__ cnt,
        double* __restrict__ entD, unsigned int* __restrict__ entI) {
    const int tile  = blockIdx.x % TILES;
    const int b     = (blockIdx.x / TILES) % B_;
    const int dir   = blockIdx.x / (TILES * B_);
    const int split = blockIdx.y;
    const float* A  = dir ? xyz2 : xyz1;
    const float* Bc = dir ? xyz1 : xyz2;

    __shared__ float4 s[CHUNK];          // {bx,by,bz,b2_f32}
    __shared__ float red[CHUNK];
    const float* bbase = Bc + ((size_t)b * N_ + (size_t)split * CHUNK) * 3;
    if (threadIdx.x < CHUNK) {
        int j = threadIdx.x;
        float bx = bbase[3 * j], by = bbase[3 * j + 1], bz = bbase[3 * j + 2];
        float b2 = bx * bx + by * by + bz * bz;
        s[j] = make_float4(bx, by, bz, b2);
        red[j] = b2;
    }
    __syncthreads();
    for (int off = CHUNK / 2; off > 0; off >>= 1) {   // max b2 in red[0]
        if (threadIdx.x < off) red[threadIdx.x] =
            fmaxf(red[threadIdx.x], red[threadIdx.x + off]);
        __syncthreads();
    }
    const float b2max = red[0];

    const size_t ob = (size_t)dir * B_ + b;
    const size_t sm = (ob * JSPLIT + split) * N_;

    #pragma unroll
    for (int pi = 0; pi < PPT; ++pi) {
        const int p = tile * (PTS * PPT) + pi * PTS + threadIdx.x;
        const float* ap = A + ((size_t)b * N_ + p) * 3;
        const float x = ap[0], y = ap[1], z = ap[2];
        const float a2f = x * x + y * y + z * z;

        const size_t o = ob * N_ + p;
        const float m  = __uint_as_float(m32[o]);
        const float me = __fmaf_rn(2e-6f, m, m);     // m*(1+2e-6)
        const float skipthr = __fmaf_rn(2e-7f, a2f + b2max, me);
        if (__uint_as_float(splitmin[sm + p]) > skipthr) continue;

        const double xd = (double)x, yd = (double)y, zd = (double)z;
        #pragma unroll 4
        for (int j = 0; j < CHUNK; ++j) {
            float4 bv = s[j];
            float dx = x - bv.x, dy = y - bv.y, dz = z - bv.z;
            float d32 = __fmaf_rn(dx, dx, __fmaf_rn(dy, dy, dz * dz));
            float thr = __fmaf_rn(2e-7f, a2f + bv.w, me);
            if (d32 <= thr) {                        // rare
                double ddx = xd - (double)bv.x;
                double ddy = yd - (double)bv.y;
                double ddz = zd - (double)bv.z;
                double d64 = fma(ddx, ddx, fma(ddy, ddy, ddz * ddz));
                unsigned int slot = atomicAdd(&cnt[o], 1u);
                if (slot < CAP) {
                    entD[o * CAP + slot] = d64;
                    entI[o * CAP + slot] = (unsigned int)(split * CHUNK + j);
                }
            }
        }
    }
}

// one thread per (dir,b,p): dmin + banded pick from candidate list
__global__ __launch_bounds__(256) void cd_pick(
        const float* __restrict__ xyz1, const float* __restrict__ xyz2,
        const unsigned int* __restrict__ cnt,
        const double* __restrict__ entD, const unsigned int* __restrict__ entI,
        double* __restrict__ dminArr, float* __restrict__ out) {
    const int gid = blockIdx.x * 256 + threadIdx.x;
    if (gid >= 2 * B_ * N_) return;
    const int dir = gid / (B_ * N_);
    const int b   = (gid / N_) % B_;
    const int p   = gid % N_;
    const float* A  = dir ? xyz2 : xyz1;
    const float* Bc = dir ? xyz1 : xyz2;
    const double tolk = dir ? TOL_K21 : TOL_K12;

    const float* ap = A + ((size_t)b * N_ + p) * 3;
    const double x = (double)ap[0], y = (double)ap[1], z = (double)ap[2];
    const double a2 = x * x + y * y + z * z;
    const float* bb = Bc + (size_t)b * N_ * 3;

    const unsigned int c = cnt[gid];
    double dmin = 1.0e300;
    unsigned int pick = 0xFFFFFFFFu;

    if (c <= CAP) {
        for (unsigned int i = 0; i < c; ++i)
            dmin = fmin(dmin, entD[(size_t)gid * CAP + i]);
        for (unsigned int i = 0; i < c; ++i) {
            unsigned int j = entI[(size_t)gid * CAP + i];
            double d = entD[(size_t)gid * CAP + i];
            double bx = (double)bb[3 * j], by = (double)bb[3 * j + 1],
                   bz = (double)bb[3 * j + 2];
            double M = a2 + (bx * bx + by * by + bz * bz);
            if (d <= fma(tolk, M, dmin)) pick = (j < pick) ? j : pick;
        }
    } else {                                      // overflow fallback (never)
        for (int j = 0; j < N_; ++j) {
            double bx = (double)bb[3 * j], by = (double)bb[3 * j + 1],
                   bz = (double)bb[3 * j + 2];
            double dx = x - bx, dy = y - by, dz = z - bz;
            dmin = fmin(dmin, fma(dx, dx, fma(dy, dy, dz * dz)));
        }
        for (int j = 0; j < N_; ++j) {
            double bx = (double)bb[3 * j], by = (double)bb[3 * j + 1],
                   bz = (double)bb[3 * j + 2];
            double dx = x - bx, dy = y - by, dz = z - bz;
            double d  = fma(dx, dx, fma(dy, dy, dz * dz));
            double M  = a2 + (bx * bx + by * by + bz * bz);
            if (d <= fma(tolk, M, dmin)) { pick = (unsigned int)j; break; }
        }
    }

    dminArr[gid] = dmin;
    const size_t obase = (dir == 0) ? (1 + (size_t)b * N_)
                                    : (1 + (size_t)B_ * N_ + (size_t)b * N_);
    out[obase + p] = (float)pick;
}

__global__ __launch_bounds__(256) void cd_finalize(
        const double* __restrict__ dminArr, float* __restrict__ out,
        double* __restrict__ loss_part) {
    const int b = blockIdx.x;
    const int t = threadIdx.x;

    double sum12 = 0.0, max12 = -1.0e300, sum21 = 0.0;
    for (int n = t; n < N_; n += 256) {
        double d12 = dminArr[(size_t)b * N_ + n];
        double d21 = dminArr[((size_t)B_ + b) * N_ + n];
        sum12 += d12;
        max12 = fmax(max12, d12);
        sum21 += d21;
    }
    __shared__ double s1[256], s2[256], s3[256];
    s1[t] = sum12; s2[t] = max12; s3[t] = sum21;
    __syncthreads();
    for (int off = 128; off > 0; off >>= 1) {
        if (t < off) {
            s1[t] += s1[t + off];
            s2[t]  = fmax(s2[t], s2[t + off]);
            s3[t] += s3[t + off];
        }
        __syncthreads();
    }
    if (t == 0) {
        loss_part[b] = s1[0] / (double)N_ + BETA_ * s2[0]
                     + (GAMMA_ + DELTA_ * (double)N_) * (s3[0] / (double)N_);
    }
}

__global__ void cd_loss(const double* __restrict__ loss_part,
                        float* __restrict__ out) {
    if (blockIdx.x == 0 && threadIdx.x == 0) {
        double s = 0.0;
        for (int b = 0; b < B_; ++b) s += loss_part[b];  // fixed order
        out[0] = (float)(s / (double)B_);
    }
}

extern "C" void kernel_launch(void* const* d_in, const int* in_sizes, int n_in,
                              void* d_out, int out_size, void* d_ws, size_t ws_size,
                              hipStream_t stream) {
    const float* xyz1 = (const float*)d_in[0];
    const float* xyz2 = (const float*)d_in[1];
    float* out = (float*)d_out;

    const size_t NP = (size_t)2 * B_ * N_;       // 32768 points
    double* entD      = (double*)d_ws;           // NP*CAP doubles (1 MiB)
    double* dminArr   = entD + NP * CAP;         // NP doubles (256 KiB)
    double* loss_part = dminArr + NP;            // B_ doubles
    unsigned int* m32 = (unsigned int*)(loss_part + B_);   // NP u32
    unsigned int* cnt = m32 + NP;                          // NP u32
    unsigned int* entI = cnt + NP;                         // NP*CAP u32
    unsigned int* splitmin = entI + NP * CAP;              // NP*JSPLIT u32 (4 MiB)

    cd_init<<<(int)((NP + 255) / 256), 256, 0, stream>>>(m32, cnt);

    dim3 grid(TILES * B_ * 2, JSPLIT);
    cd_min32<<<grid, PTS, 0, stream>>>(xyz1, xyz2, m32, splitmin);
    cd_cand <<<grid, PTS, 0, stream>>>(xyz1, xyz2, m32, splitmin, cnt, entD, entI);

    cd_pick<<<(int)((NP + 255) / 256), 256, 0, stream>>>(
        xyz1, xyz2, cnt, entD, entI, dminArr, out);

    cd_finalize<<<B_, 256, 0, stream>>>(dminArr, out, loss_part);
    cd_loss<<<1, 64, 0, stream>>>(loss_part, out);
}

// Round 18
// 49.380 us; speedup vs baseline: 2.7515x; 1.8257x over previous
//
#include <hip/hip_runtime.h>
#include <stdint.h>
#include <float.h>

// Chamfer distance, B=4, N=M=4096, 3D fp32.
// Outputs (flat, float32): [0] loss, [1..16384] idx12 (float), [16385..32768] idx21.
//
// SEMANTIC CONTRACT (validated R14-R17, absmax 0.0 — do not change):
//   d in f64: d = fma(dx,dx, fma(dy,dy, dz*dz)), dx = x - bx (f64-promoted f32)
//   pick = smallest index j with d_j <= fma(TOL_K(dir), a2 + b2_j, dmin)
//     (a2, b2_j computed in f64 from promoted f32 coords)
//   K12 = 0.6*2^-23, K21 = 0.   dmin = exact f64 min.
//
// R18: one WAVE owns one point end-to-end (R17's cd_cand was divergence-bound:
// per-thread skip left ~every wave executing the j-loop exec-masked).
// cd_min32: f32 sweep -> splitmin[ob][split][p] (no atomics).
// cd_select: wave reduces m over 32 splitmin (== atomicMin result), ballots the
// survivor mask (conservative skip bound, no b2max needed:
//   skip if splitmin > (m(1+2e-6) + 7e-7*a2f)(1+4e-6), from b2<=2(a2+d)),
// then 2-pass scans surviving splits: pass1 f64 dmin over prefilter survivors
// (true argmin provably survives: R16 margins), pass2 contract-pick. All
// candidate arithmetic identical to R17's cd_cand/cd_pick.

constexpr int B_ = 4;
constexpr int N_ = 4096;
constexpr int PTS = 256;                 // threads per block (min32)
constexpr int PPT = 2;                   // points per thread (min32)
constexpr int TILES = N_ / (PTS * PPT);  // 8
constexpr int JSPLIT = 32;
constexpr int CHUNK = N_ / JSPLIT;       // 128
constexpr double EPS32 = 1.1920928955078125e-7;  // 2^-23
constexpr double TOL_K12 = 0.6 * EPS32;
constexpr double TOL_K21 = 0.0;
constexpr double BETA_ = 1.0;
constexpr double GAMMA_ = 1.0;
constexpr double DELTA_ = 0.0;

// grid: (TILES*B_*2, JSPLIT); blockIdx.x = tile + TILES*(b + B_*dir)
__global__ __launch_bounds__(256) void cd_min32(
        const float* __restrict__ xyz1, const float* __restrict__ xyz2,
        unsigned int* __restrict__ splitmin) {
    const int tile  = blockIdx.x % TILES;
    const int b     = (blockIdx.x / TILES) % B_;
    const int dir   = blockIdx.x / (TILES * B_);
    const int split = blockIdx.y;
    const float* A  = dir ? xyz2 : xyz1;
    const float* Bc = dir ? xyz1 : xyz2;

    __shared__ float4 s[CHUNK];          // 2 KiB
    const float* bbase = Bc + ((size_t)b * N_ + (size_t)split * CHUNK) * 3;
    if (threadIdx.x < CHUNK) {
        int j = threadIdx.x;
        s[j] = make_float4(bbase[3 * j], bbase[3 * j + 1], bbase[3 * j + 2], 0.f);
    }
    __syncthreads();

    const int p0 = tile * (PTS * PPT) + threadIdx.x;
    const int p1 = p0 + PTS;
    const float* ap0 = A + ((size_t)b * N_ + p0) * 3;
    const float* ap1 = A + ((size_t)b * N_ + p1) * 3;
    const float x0 = ap0[0], y0 = ap0[1], z0 = ap0[2];
    const float x1 = ap1[0], y1 = ap1[1], z1 = ap1[2];

    float m0 = FLT_MAX, m1 = FLT_MAX;
    #pragma unroll 8
    for (int j = 0; j < CHUNK; ++j) {
        float4 bv = s[j];
        float dx0 = x0 - bv.x, dy0 = y0 - bv.y, dz0 = z0 - bv.z;
        float dx1 = x1 - bv.x, dy1 = y1 - bv.y, dz1 = z1 - bv.z;
        m0 = fminf(m0, __fmaf_rn(dx0, dx0, __fmaf_rn(dy0, dy0, dz0 * dz0)));
        m1 = fminf(m1, __fmaf_rn(dx1, dx1, __fmaf_rn(dy1, dy1, dz1 * dz1)));
    }
    const size_t ob = (size_t)dir * B_ + b;
    const size_t sm = (ob * JSPLIT + split) * N_;
    splitmin[sm + p0] = __float_as_uint(m0);     // block-owned: plain store
    splitmin[sm + p1] = __float_as_uint(m1);
}

// one wave per point; grid: (2*B_*N_)/4 blocks of 256 (4 waves/block)
__global__ __launch_bounds__(256) void cd_select(
        const float* __restrict__ xyz1, const float* __restrict__ xyz2,
        const unsigned int* __restrict__ splitmin,
        double* __restrict__ dminArr, float* __restrict__ out) {
    const int w    = blockIdx.x * 4 + (threadIdx.x >> 6);   // point id
    const int lane = threadIdx.x & 63;
    const int dir  = w / (B_ * N_);
    const int b    = (w / N_) % B_;
    const int p    = w % N_;
    const float* A  = dir ? xyz2 : xyz1;
    const float* Bc = dir ? xyz1 : xyz2;
    const double tolk = dir ? TOL_K21 : TOL_K12;
    const size_t ob = (size_t)dir * B_ + b;

    const float* ap = A + ((size_t)b * N_ + p) * 3;
    const float x = ap[0], y = ap[1], z = ap[2];
    const float a2f = x * x + y * y + z * z;

    // m = min over 32 per-split minima (== R17's atomicMin m32, bit-identical)
    const int l32 = lane & 31;
    const float sv = __uint_as_float(splitmin[(ob * JSPLIT + l32) * N_ + p]);
    float m = sv;
    #pragma unroll
    for (int off = 1; off < 32; off <<= 1)
        m = fminf(m, __shfl_xor(m, off));

    const float me = __fmaf_rn(2e-6f, m, m);     // m*(1+2e-6)
    // conservative split skip (no b2max needed): from b2 <= 2(a2+d),
    // any j passing d32<=thr has d32 <= (me + 6.1e-7*a2f)(1+4.2e-7)
    const float skipthr = (me + 7e-7f * a2f) * (1.0f + 4e-6f);
    unsigned int mask = (unsigned int)__ballot(lane < 32 && sv <= skipthr);

    const float* bb = Bc + (size_t)b * N_ * 3;
    const double xd = (double)x, yd = (double)y, zd = (double)z;
    const double a2 = xd * xd + yd * yd + zd * zd;

    // pass 1: f64 dmin over prefilter survivors (true argmin provably among them)
    double dmin = 1.0e300;
    unsigned int mk = mask;
    while (mk) {
        int s = __ffs(mk) - 1; mk &= mk - 1;
        int j = s * CHUNK + lane;
        #pragma unroll
        for (int k = 0; k < 2; ++k, j += 64) {
            float bx = bb[3 * j], by = bb[3 * j + 1], bz = bb[3 * j + 2];
            float dx = x - bx, dy = y - by, dz = z - bz;
            float d32 = __fmaf_rn(dx, dx, __fmaf_rn(dy, dy, dz * dz));
            float thr = __fmaf_rn(2e-7f, a2f + (bx * bx + by * by + bz * bz), me);
            if (d32 <= thr) {
                double ddx = xd - (double)bx, ddy = yd - (double)by,
                       ddz = zd - (double)bz;
                dmin = fmin(dmin, fma(ddx, ddx, fma(ddy, ddy, ddz * ddz)));
            }
        }
    }
    #pragma unroll
    for (int off = 1; off < 64; off <<= 1)
        dmin = fmin(dmin, __shfl_xor(dmin, off));

    // pass 2: smallest index with d64 <= fma(tolk, M64, dmin)  [contract]
    unsigned int pick = 0xFFFFFFFFu;
    mk = mask;
    while (mk) {
        int s = __ffs(mk) - 1; mk &= mk - 1;
        int j = s * CHUNK + lane;
        #pragma unroll
        for (int k = 0; k < 2; ++k, j += 64) {
            float bx = bb[3 * j], by = bb[3 * j + 1], bz = bb[3 * j + 2];
            float dx = x - bx, dy = y - by, dz = z - bz;
            float d32 = __fmaf_rn(dx, dx, __fmaf_rn(dy, dy, dz * dz));
            float thr = __fmaf_rn(2e-7f, a2f + (bx * bx + by * by + bz * bz), me);
            if (d32 <= thr) {
                double bxd = (double)bx, byd = (double)by, bzd = (double)bz;
                double ddx = xd - bxd, ddy = yd - byd, ddz = zd - bzd;
                double d64 = fma(ddx, ddx, fma(ddy, ddy, ddz * ddz));
                double M   = a2 + (bxd * bxd + byd * byd + bzd * bzd);
                if (d64 <= fma(tolk, M, dmin))
                    pick = (pick < (unsigned int)j) ? pick : (unsigned int)j;
            }
        }
    }
    #pragma unroll
    for (int off = 1; off < 64; off <<= 1) {
        unsigned int o2 = (unsigned int)__shfl_xor((int)pick, off);
        pick = (o2 < pick) ? o2 : pick;
    }

    if (lane == 0) {
        dminArr[w] = dmin;
        const size_t obase = (dir == 0) ? (1 + (size_t)b * N_)
                                        : (1 + (size_t)B_ * N_ + (size_t)b * N_);
        out[obase + p] = (float)pick;
    }
}

__global__ __launch_bounds__(256) void cd_finalize(
        const double* __restrict__ dminArr, float* __restrict__ out,
        double* __restrict__ loss_part) {
    const int b = blockIdx.x;
    const int t = threadIdx.x;

    double sum12 = 0.0, max12 = -1.0e300, sum21 = 0.0;
    for (int n = t; n < N_; n += 256) {
        double d12 = dminArr[(size_t)b * N_ + n];
        double d21 = dminArr[((size_t)B_ + b) * N_ + n];
        sum12 += d12;
        max12 = fmax(max12, d12);
        sum21 += d21;
    }
    __shared__ double s1[256], s2[256], s3[256];
    s1[t] = sum12; s2[t] = max12; s3[t] = sum21;
    __syncthreads();
    for (int off = 128; off > 0; off >>= 1) {
        if (t < off) {
            s1[t] += s1[t + off];
            s2[t]  = fmax(s2[t], s2[t + off]);
            s3[t] += s3[t + off];
        }
        __syncthreads();
    }
    if (t == 0) {
        loss_part[b] = s1[0] / (double)N_ + BETA_ * s2[0]
                     + (GAMMA_ + DELTA_ * (double)N_) * (s3[0] / (double)N_);
    }
}

__global__ void cd_loss(const double* __restrict__ loss_part,
                        float* __restrict__ out) {
    if (blockIdx.x == 0 && threadIdx.x == 0) {
        double s = 0.0;
        for (int b = 0; b < B_; ++b) s += loss_part[b];  // fixed order
        out[0] = (float)(s / (double)B_);
    }
}

extern "C" void kernel_launch(void* const* d_in, const int* in_sizes, int n_in,
                              void* d_out, int out_size, void* d_ws, size_t ws_size,
                              hipStream_t stream) {
    const float* xyz1 = (const float*)d_in[0];
    const float* xyz2 = (const float*)d_in[1];
    float* out = (float*)d_out;

    const size_t NP = (size_t)2 * B_ * N_;       // 32768 points
    double* dminArr   = (double*)d_ws;           // NP doubles (256 KiB)
    double* loss_part = dminArr + NP;            // B_ doubles
    unsigned int* splitmin = (unsigned int*)(loss_part + B_);  // NP*JSPLIT (4 MiB)

    dim3 grid(TILES * B_ * 2, JSPLIT);
    cd_min32<<<grid, PTS, 0, stream>>>(xyz1, xyz2, splitmin);

    cd_select<<<(int)(NP / 4), 256, 0, stream>>>(xyz1, xyz2, splitmin,
                                                 dminArr, out);

    cd_finalize<<<B_, 256, 0, stream>>>(dminArr, out, loss_part);
    cd_loss<<<1, 64, 0, stream>>>(loss_part, out);
}

// Round 19
// 49.181 us; speedup vs baseline: 2.7626x; 1.0040x over previous
//
#include <hip/hip_runtime.h>
#include <stdint.h>
#include <float.h>

// Chamfer distance, B=4, N=M=4096, 3D fp32.
// Outputs (flat, float32): [0] loss, [1..16384] idx12 (float), [16385..32768] idx21.
//
// SEMANTIC CONTRACT (validated R14-R18, absmax 0.0 — do not change):
//   d in f64: d = fma(dx,dx, fma(dy,dy, dz*dz)), dx = x - bx (f64-promoted f32)
//   pick = smallest index j with d_j <= fma(TOL_K(dir), a2 + b2_j, dmin)
//     (a2, b2_j in f64 from promoted f32 coords)
//   K12 = 0.6*2^-23, K21 = 0.   dmin = exact f64 min.
//   Prefilter (R16-proven 2x margin): survivor iff
//     d32 <= fma(2e-7, a2f+b2f_j, m*(1+2e-6)), m = global f32 min (fma d32).
//
// R19: cd_min32 was LDS-issue-bound (1 ds_read_b128 per 14 VALU; ~12cyc LDS
// pipe per read => ~20us). PPT=8 amortizes each ds_read over 8 points
// (56 VALU/read) -> VALU-issue-bound ~6-8us. cd_select unchanged from R18.

constexpr int B_ = 4;
constexpr int N_ = 4096;
constexpr int PTS = 256;                 // threads per block (min32)
constexpr int PPT = 8;                   // points per thread (min32)
constexpr int TILES = N_ / (PTS * PPT);  // 2
constexpr int JSPLIT = 32;
constexpr int CHUNK = N_ / JSPLIT;       // 128
constexpr double EPS32 = 1.1920928955078125e-7;  // 2^-23
constexpr double TOL_K12 = 0.6 * EPS32;
constexpr double TOL_K21 = 0.0;
constexpr double BETA_ = 1.0;
constexpr double GAMMA_ = 1.0;
constexpr double DELTA_ = 0.0;

// grid: (TILES*B_*2, JSPLIT); blockIdx.x = tile + TILES*(b + B_*dir)
__global__ __launch_bounds__(256) void cd_min32(
        const float* __restrict__ xyz1, const float* __restrict__ xyz2,
        unsigned int* __restrict__ splitmin) {
    const int tile  = blockIdx.x % TILES;
    const int b     = (blockIdx.x / TILES) % B_;
    const int dir   = blockIdx.x / (TILES * B_);
    const int split = blockIdx.y;
    const float* A  = dir ? xyz2 : xyz1;
    const float* Bc = dir ? xyz1 : xyz2;

    __shared__ float4 s[CHUNK];          // 2 KiB
    const float* bbase = Bc + ((size_t)b * N_ + (size_t)split * CHUNK) * 3;
    if (threadIdx.x < CHUNK) {
        int j = threadIdx.x;
        s[j] = make_float4(bbase[3 * j], bbase[3 * j + 1], bbase[3 * j + 2], 0.f);
    }
    __syncthreads();

    float px[PPT], py[PPT], pz[PPT], mn[PPT];
    #pragma unroll
    for (int pi = 0; pi < PPT; ++pi) {
        const int p = tile * (PTS * PPT) + pi * PTS + threadIdx.x;
        const float* ap = A + ((size_t)b * N_ + p) * 3;
        px[pi] = ap[0]; py[pi] = ap[1]; pz[pi] = ap[2];
        mn[pi] = FLT_MAX;
    }

    #pragma unroll 4
    for (int j = 0; j < CHUNK; ++j) {
        float4 bv = s[j];
        #pragma unroll
        for (int pi = 0; pi < PPT; ++pi) {
            float dx = px[pi] - bv.x, dy = py[pi] - bv.y, dz = pz[pi] - bv.z;
            mn[pi] = fminf(mn[pi],
                           __fmaf_rn(dx, dx, __fmaf_rn(dy, dy, dz * dz)));
        }
    }

    const size_t ob = (size_t)dir * B_ + b;
    const size_t sm = (ob * JSPLIT + split) * N_;
    #pragma unroll
    for (int pi = 0; pi < PPT; ++pi) {
        const int p = tile * (PTS * PPT) + pi * PTS + threadIdx.x;
        splitmin[sm + p] = __float_as_uint(mn[pi]);   // block-owned store
    }
}

// one wave per point; grid: (2*B_*N_)/4 blocks of 256 (4 waves/block)
__global__ __launch_bounds__(256) void cd_select(
        const float* __restrict__ xyz1, const float* __restrict__ xyz2,
        const unsigned int* __restrict__ splitmin,
        double* __restrict__ dminArr, float* __restrict__ out) {
    const int w    = blockIdx.x * 4 + (threadIdx.x >> 6);   // point id
    const int lane = threadIdx.x & 63;
    const int dir  = w / (B_ * N_);
    const int b    = (w / N_) % B_;
    const int p    = w % N_;
    const float* A  = dir ? xyz2 : xyz1;
    const float* Bc = dir ? xyz1 : xyz2;
    const double tolk = dir ? TOL_K21 : TOL_K12;
    const size_t ob = (size_t)dir * B_ + b;

    const float* ap = A + ((size_t)b * N_ + p) * 3;
    const float x = ap[0], y = ap[1], z = ap[2];
    const float a2f = x * x + y * y + z * z;

    // m = min over 32 per-split minima (== global f32 min, bit-identical)
    const int l32 = lane & 31;
    const float sv = __uint_as_float(splitmin[(ob * JSPLIT + l32) * N_ + p]);
    float m = sv;
    #pragma unroll
    for (int off = 1; off < 32; off <<= 1)
        m = fminf(m, __shfl_xor(m, off));

    const float me = __fmaf_rn(2e-6f, m, m);     // m*(1+2e-6)
    // conservative split skip (from b2 <= 2(a2+d), R18-validated)
    const float skipthr = (me + 7e-7f * a2f) * (1.0f + 4e-6f);
    unsigned int mask = (unsigned int)__ballot(lane < 32 && sv <= skipthr);

    const float* bb = Bc + (size_t)b * N_ * 3;
    const double xd = (double)x, yd = (double)y, zd = (double)z;
    const double a2 = xd * xd + yd * yd + zd * zd;

    // pass 1: f64 dmin over prefilter survivors (true argmin provably among them)
    double dmin = 1.0e300;
    unsigned int mk = mask;
    while (mk) {
        int s = __ffs(mk) - 1; mk &= mk - 1;
        int j = s * CHUNK + lane;
        #pragma unroll
        for (int k = 0; k < 2; ++k, j += 64) {
            float bx = bb[3 * j], by = bb[3 * j + 1], bz = bb[3 * j + 2];
            float dx = x - bx, dy = y - by, dz = z - bz;
            float d32 = __fmaf_rn(dx, dx, __fmaf_rn(dy, dy, dz * dz));
            float thr = __fmaf_rn(2e-7f, a2f + (bx * bx + by * by + bz * bz), me);
            if (d32 <= thr) {
                double ddx = xd - (double)bx, ddy = yd - (double)by,
                       ddz = zd - (double)bz;
                dmin = fmin(dmin, fma(ddx, ddx, fma(ddy, ddy, ddz * ddz)));
            }
        }
    }
    #pragma unroll
    for (int off = 1; off < 64; off <<= 1)
        dmin = fmin(dmin, __shfl_xor(dmin, off));

    // pass 2: smallest index with d64 <= fma(tolk, M64, dmin)  [contract]
    unsigned int pick = 0xFFFFFFFFu;
    mk = mask;
    while (mk) {
        int s = __ffs(mk) - 1; mk &= mk - 1;
        int j = s * CHUNK + lane;
        #pragma unroll
        for (int k = 0; k < 2; ++k, j += 64) {
            float bx = bb[3 * j], by = bb[3 * j + 1], bz = bb[3 * j + 2];
            float dx = x - bx, dy = y - by, dz = z - bz;
            float d32 = __fmaf_rn(dx, dx, __fmaf_rn(dy, dy, dz * dz));
            float thr = __fmaf_rn(2e-7f, a2f + (bx * bx + by * by + bz * bz), me);
            if (d32 <= thr) {
                double bxd = (double)bx, byd = (double)by, bzd = (double)bz;
                double ddx = xd - bxd, ddy = yd - byd, ddz = zd - bzd;
                double d64 = fma(ddx, ddx, fma(ddy, ddy, ddz * ddz));
                double M   = a2 + (bxd * bxd + byd * byd + bzd * bzd);
                if (d64 <= fma(tolk, M, dmin))
                    pick = (pick < (unsigned int)j) ? pick : (unsigned int)j;
            }
        }
    }
    #pragma unroll
    for (int off = 1; off < 64; off <<= 1) {
        unsigned int o2 = (unsigned int)__shfl_xor((int)pick, off);
        pick = (o2 < pick) ? o2 : pick;
    }

    if (lane == 0) {
        dminArr[w] = dmin;
        const size_t obase = (dir == 0) ? (1 + (size_t)b * N_)
                                        : (1 + (size_t)B_ * N_ + (size_t)b * N_);
        out[obase + p] = (float)pick;
    }
}

__global__ __launch_bounds__(256) void cd_finalize(
        const double* __restrict__ dminArr, float* __restrict__ out,
        double* __restrict__ loss_part) {
    const int b = blockIdx.x;
    const int t = threadIdx.x;

    double sum12 = 0.0, max12 = -1.0e300, sum21 = 0.0;
    for (int n = t; n < N_; n += 256) {
        double d12 = dminArr[(size_t)b * N_ + n];
        double d21 = dminArr[((size_t)B_ + b) * N_ + n];
        sum12 += d12;
        max12 = fmax(max12, d12);
        sum21 += d21;
    }
    __shared__ double s1[256], s2[256], s3[256];
    s1[t] = sum12; s2[t] = max12; s3[t] = sum21;
    __syncthreads();
    for (int off = 128; off > 0; off >>= 1) {
        if (t < off) {
            s1[t] += s1[t + off];
            s2[t]  = fmax(s2[t], s2[t + off]);
            s3[t] += s3[t + off];
        }
        __syncthreads();
    }
    if (t == 0) {
        loss_part[b] = s1[0] / (double)N_ + BETA_ * s2[0]
                     + (GAMMA_ + DELTA_ * (double)N_) * (s3[0] / (double)N_);
    }
}

__global__ void cd_loss(const double* __restrict__ loss_part,
                        float* __restrict__ out) {
    if (blockIdx.x == 0 && threadIdx.x == 0) {
        double s = 0.0;
        for (int b = 0; b < B_; ++b) s += loss_part[b];  // fixed order
        out[0] = (float)(s / (double)B_);
    }
}

extern "C" void kernel_launch(void* const* d_in, const int* in_sizes, int n_in,
                              void* d_out, int out_size, void* d_ws, size_t ws_size,
                              hipStream_t stream) {
    const float* xyz1 = (const float*)d_in[0];
    const float* xyz2 = (const float*)d_in[1];
    float* out = (float*)d_out;

    const size_t NP = (size_t)2 * B_ * N_;       // 32768 points
    double* dminArr   = (double*)d_ws;           // NP doubles (256 KiB)
    double* loss_part = dminArr + NP;            // B_ doubles
    unsigned int* splitmin = (unsigned int*)(loss_part + B_);  // NP*JSPLIT (4 MiB)

    dim3 grid(TILES * B_ * 2, JSPLIT);
    cd_min32<<<grid, PTS, 0, stream>>>(xyz1, xyz2, splitmin);

    cd_select<<<(int)(NP / 4), 256, 0, stream>>>(xyz1, xyz2, splitmin,
                                                 dminArr, out);

    cd_finalize<<<B_, 256, 0, stream>>>(dminArr, out, loss_part);
    cd_loss<<<1, 64, 0, stream>>>(loss_part, out);
}